// Round 1
// baseline (714.575 us; speedup 1.0000x reference)
//
#include <hip/hip_runtime.h>

// ---------------------------------------------------------------------------
// out[b][o][12h+i][w] = sum_c x_i[b][c][h][w] * W[c][o] + bias[o]*count[12h+i]
// GEMM: M=393216 pixels, K=256, N=256.  Memory-bound (806 MB traffic, 51.5 GF)
// -> bf16 MFMA 16x16x32, W in registers per-wave, x staged via LDS transpose.
// ---------------------------------------------------------------------------

typedef __attribute__((ext_vector_type(8))) short bf16x8;
typedef __attribute__((ext_vector_type(4))) float f32x4;

#define ROW_B 512          // LDS row stride bytes: 256 ch * 2B (no pad, 64KB cap)
#define TILE_B (64 * ROW_B)

struct Ptrs12 { const float* p[12]; };

__device__ __forceinline__ unsigned f2bf1(float f) {
  unsigned u = __float_as_uint(f);
  return (u + 0x7FFFu + ((u >> 16) & 1u)) >> 16;   // RNE f32 -> bf16 bits
}

// Pre-swizzle W (fp32 [c][o]) into bf16 MFMA B-fragment order:
// Wf[u][s][lane][j], u = o-tile (0..15), s = k-step (0..7),
// lane: n = u*16 + (lane&15), k = s*32 + (lane>>4)*8 + j
__global__ void w_prepass(const float* __restrict__ W, unsigned short* __restrict__ Wf) {
  int idx = blockIdx.x * 256 + threadIdx.x;   // 65536 total
  int j = idx & 7, l = (idx >> 3) & 63, s = (idx >> 9) & 7, u = idx >> 12;
  int c = s * 32 + (l >> 4) * 8 + j;
  int o = u * 16 + (l & 15);
  Wf[idx] = (unsigned short)f2bf1(W[c * 256 + o]);
}

__global__ __launch_bounds__(512, 2) void gemm12(Ptrs12 xs,
                                                 const unsigned short* __restrict__ Wf,
                                                 const float* __restrict__ bias,
                                                 float* __restrict__ out) {
  __shared__ char smem[2 * TILE_B];           // double-buffered x tile, 64 KB
  const int tid = threadIdx.x;
  const int v = tid >> 6;                     // wave 0..7 (N-slice owner)
  const int l = tid & 63;
  const int q = l >> 4;                       // quad 0..3
  const int m = l & 15;

  // W fragments for this wave's 32 outputs, all K: 16 frags = 64 VGPRs.
  bf16x8 wf[2][8];
#pragma unroll
  for (int tt = 0; tt < 2; ++tt)
#pragma unroll
    for (int s = 0; s < 8; ++s) {
      int u = v * 2 + tt;
      wf[tt][s] = *(const bf16x8*)(Wf + (((u * 8 + s) * 64 + l) << 3));
    }
  const float bv0 = bias[v * 32 + m];
  const float bv1 = bias[v * 32 + 16 + m];

  const int tile0 = blockIdx.x * 12;          // 512 blocks * 12 tiles = 6144
  float4 pf[2][4];                            // global prefetch regs (32 VGPR)

  // Global loads for one 64px x 256ch tile: fully coalesced float4s.
  // Thread covers channels {it*128 + v*16 + q*4 .. +3} at w = w0 + m*4 .. +3
  auto tload = [&](int tile) {
    int row = tile >> 2, w0 = (tile & 3) << 6;
    int i = row >> 7, bb = (row >> 6) & 1, h = row & 63;
    const float* xp = xs.p[i] + (size_t)bb * 4194304 + h * 256 + w0 + m * 4;
#pragma unroll
    for (int it = 0; it < 2; ++it) {
      int cb = it * 128 + v * 16 + q * 4;
#pragma unroll
      for (int dc = 0; dc < 4; ++dc)
        pf[it][dc] = *(const float4*)(xp + (size_t)(cb + dc) * 16384);
    }
  };
  // Convert + transpose into LDS [w][c] bf16; 4 channels packed -> ds_write_b64
  auto twrite = [&](int bs) {
    char* lb = smem + bs * TILE_B;
#pragma unroll
    for (int it = 0; it < 2; ++it) {
      int cb = it * 128 + v * 16 + q * 4;
#pragma unroll
      for (int k = 0; k < 4; ++k) {
        unsigned lo = f2bf1(((const float*)&pf[it][0])[k]) |
                      (f2bf1(((const float*)&pf[it][1])[k]) << 16);
        unsigned hi = f2bf1(((const float*)&pf[it][2])[k]) |
                      (f2bf1(((const float*)&pf[it][3])[k]) << 16);
        uint2 val; val.x = lo; val.y = hi;
        *(uint2*)(lb + (m * 4 + k) * ROW_B + cb * 2) = val;
      }
    }
  };

  tload(tile0);
  twrite(0);
  __syncthreads();

#pragma unroll 1
  for (int mt = 0; mt < 12; ++mt) {
    int tile = tile0 + mt;
    if (mt < 11) tload(tile + 1);             // issue next tile's global loads

    f32x4 acc[4][2];
#pragma unroll
    for (int a = 0; a < 4; ++a) { acc[a][0] = 0.0f; acc[a][1] = 0.0f; }

    const char* lb = smem + (mt & 1) * TILE_B;
#pragma unroll
    for (int s = 0; s < 8; ++s) {
      bf16x8 af[4];
#pragma unroll
      for (int m16 = 0; m16 < 4; ++m16)       // A frag: pixel = m16*16+m, k = s*32+q*8+j
        af[m16] = *(const bf16x8*)(lb + (m16 * 16 + m) * ROW_B + s * 64 + q * 16);
#pragma unroll
      for (int m16 = 0; m16 < 4; ++m16) {
        acc[m16][0] = __builtin_amdgcn_mfma_f32_16x16x32_bf16(af[m16], wf[0][s], acc[m16][0], 0, 0, 0);
        acc[m16][1] = __builtin_amdgcn_mfma_f32_16x16x32_bf16(af[m16], wf[1][s], acc[m16][1], 0, 0, 0);
      }
    }

    if (mt < 11) twrite((mt + 1) & 1);        // drain prefetch into other buffer

    // Epilogue: bias*count + coalesced float4 stores.
    // C/D layout: col(o) = lane&15, row(pixel) = q*4 + reg -> regs are 4 consecutive w.
    int row = tile >> 2, w0 = (tile & 3) << 6;
    int i = row >> 7, bb = (row >> 6) & 1, h = row & 63;
    int r = h * 12 + i;
    int cnt_i = (r < 11 ? r : 11) - (r > 756 ? r - 756 : 0) + 1;
    float cnt = (float)cnt_i;
    size_t ob = (size_t)bb * 50331648u + (size_t)r * 256 + w0 + q * 4;
#pragma unroll
    for (int tt = 0; tt < 2; ++tt) {
      float ba = (tt ? bv1 : bv0) * cnt;
      float* op = out + ob + (size_t)(v * 32 + tt * 16 + m) * 196608;
#pragma unroll
      for (int m16 = 0; m16 < 4; ++m16) {
        float4 sv;
        sv.x = acc[m16][tt][0] + ba;
        sv.y = acc[m16][tt][1] + ba;
        sv.z = acc[m16][tt][2] + ba;
        sv.w = acc[m16][tt][3] + ba;
        *(float4*)(op + m16 * 16) = sv;
      }
    }
    __syncthreads();
  }
}

extern "C" void kernel_launch(void* const* d_in, const int* in_sizes, int n_in,
                              void* d_out, int out_size, void* d_ws, size_t ws_size,
                              hipStream_t stream) {
  Ptrs12 xs;
  for (int i = 0; i < 12; ++i) xs.p[i] = (const float*)d_in[i];
  const float* W = (const float*)d_in[12];
  const float* bias = (const float*)d_in[13];
  unsigned short* Wf = (unsigned short*)d_ws;   // 128 KB bf16 swizzled W

  hipLaunchKernelGGL(w_prepass, dim3(256), dim3(256), 0, stream, W, Wf);
  hipLaunchKernelGGL(gemm12, dim3(512), dim3(512), 0, stream, xs, Wf, bias, (float*)d_out);
}